// Round 2
// baseline (2646.926 us; speedup 1.0000x reference)
//
#include <hip/hip_runtime.h>
#include <stdint.h>

#define EN 120000
#define NN 12000
#define FF 768

typedef __attribute__((ext_vector_type(8))) short short8;
typedef __attribute__((ext_vector_type(4))) short short4v;
typedef __attribute__((ext_vector_type(4))) float floatx4;
typedef __attribute__((ext_vector_type(2))) float floatx2;

#ifdef __has_builtin
#if __has_builtin(__builtin_amdgcn_cvt_pk_f32_fp8) && __has_builtin(__builtin_amdgcn_cvt_f32_fp8)
#define HAS_HW_FP8 1
#endif
#endif
#ifndef HAS_HW_FP8
#define HAS_HW_FP8 0
#endif

__device__ __forceinline__ float b2f(short u) {
  union { uint32_t i; float f; } v; v.i = ((uint32_t)(uint16_t)u) << 16; return v.f;
}
__device__ __forceinline__ short f2b(float f) {
  union { float f; uint32_t i; } v; v.f = f;
  uint32_t r = (v.i + 0x7fffu + ((v.i >> 16) & 1u)) >> 16;
  return (short)(uint16_t)r;
}
// fp8 e4m3fn software codec (OCP; exact via f32 subnormal scaling; RNE)
__device__ __forceinline__ float f8tof(uint32_t b) {
  union { uint32_t i; float f; } u;
  u.i = (b & 0x7f) << 20;
  float v = u.f * 0x1p120f;
  return (b & 0x80) ? -v : v;
}
__device__ __forceinline__ uint8_t ftof8(float v) {
  union { float f; uint32_t i; } u;
  u.f = fabsf(v) * 0x1p-120f;
  uint32_t r = (u.i + 0x7ffffu + ((u.i >> 20) & 1u)) >> 20;
  if (r > 0x7eu) r = 0x7eu;                 // clamp to 448, no inf/nan
  return (uint8_t)(r | ((v < 0.f) ? 0x80u : 0u));
}
// decode fp8 pair in bytes 0..1 of u
__device__ __forceinline__ floatx2 f8pair(uint32_t u) {
#if HAS_HW_FP8
  return __builtin_amdgcn_cvt_pk_f32_fp8(u, false);
#else
  floatx2 r; r.x = f8tof(u & 0xff); r.y = f8tof((u >> 8) & 0xff); return r;
#endif
}
__device__ __forceinline__ floatx2 f8pair_hi(uint32_t u) {
#if HAS_HW_FP8
  return __builtin_amdgcn_cvt_pk_f32_fp8(u, true);
#else
  floatx2 r; r.x = f8tof((u >> 16) & 0xff); r.y = f8tof((u >> 24) & 0xff); return r;
#endif
}
__device__ __forceinline__ float f8one(uint32_t u) {   // byte 0
#if HAS_HW_FP8
  return __builtin_amdgcn_cvt_f32_fp8(u, 0);
#else
  return f8tof(u & 0xff);
#endif
}
__device__ __forceinline__ float sigm(float x) { return 1.f / (1.f + __expf(-x)); }
__device__ __forceinline__ float tanh_fast(float x) {
  float ax = fabsf(x);
  float t = __expf(-2.f * ax);
  float r = (1.f - t) / (1.f + t);
  return copysignf(r, x);
}
__device__ __forceinline__ void async_ld16(const void* g, void* l) {
  __builtin_amdgcn_global_load_lds(
      (const __attribute__((address_space(1))) void*)g,
      (__attribute__((address_space(3))) void*)l, 16, 0, 0);
}

// ---------------------------------------------------------------------------
// Fused multi-weight GEMM: C_w[M,N] = A[M,K](bf16) @ Bt_w[N,K](bf16)^T
// Block tile 64(M) x 128(N), BK=32, 4 waves (each wave: 64x32, 4x2 16x16x32).
//
// K-loop: T3/T4 counted-vmcnt double buffer. stage(t+2) is issued at the END
// of iteration t; iteration t+1 waits only vmcnt(NL) (NL = loads of the
// NEWEST stage), so tile t+2's loads stay in flight across the whole of
// iteration t+1. No vmcnt(0) in the main loop (m218: the counted wait IS the
// gain). Uniform count maintained past loop end by dummy re-stages of the
// last K-tile (vmcnt retires in order; dummies land in the just-consumed
// buffer, content never read).
//
// Block swizzle: bijective XCD remap (8 XCDs) so the gridDim.x N-blocks
// sharing one A row-panel land contiguously on one XCD (R1: FETCH 252->182MB).
//
// P node-row layout (fp8, 4608 B): [fsT pairs 1536 | fsM pairs 1536 | eT 768 | eM 768]
// EPI 0: store fp8 into P with pair-interleaved mapping (node projections)
// EPI 1: tanh(v + bias0) -> bf16 (pre_edge)
// EPI 2: conv1 msg atomics + gate -> e2 fp8 (NW=3: f,s,e)
// EPI 3: conv2 msg atomics (NW=2: f,s)
// ---------------------------------------------------------------------------
template <int NW, int EPI>
__global__ __launch_bounds__(256, 2) void gemm_fused(
    const short* __restrict__ A, int lda,
    const short* __restrict__ Bt, int ldb, int wstride,
    int M, int N, int K,
    void* __restrict__ outP, int ldout,
    const float* __restrict__ bias0, const float* __restrict__ bias1,
    const float* __restrict__ bias2,
    const int* __restrict__ dst, const int* __restrict__ src,
    const uint8_t* __restrict__ Pn, int pstride,
    const short* __restrict__ eIn, uint8_t* __restrict__ e2Out,
    float* __restrict__ agg)
{
  constexpr int NL = NW * 2 + 1;        // global_load_lds issues per stage
  __shared__ alignas(16) short lA[2][64 * 32];
  __shared__ alignas(16) short lB[2][NW * 128 * 32];

  const int tid  = threadIdx.x;
  const int wave = tid >> 6;
  const int lane = tid & 63;
  const int quad = lane >> 4;
  const int l16  = lane & 15;

  // ---- bijective XCD swizzle (m204 formula) ----
  const int gx  = gridDim.x;
  const int nwg = gx * gridDim.y;
  int flat = blockIdx.y * gx + blockIdx.x;
  {
    const int q = nwg >> 3, r = nwg & 7;
    const int xcd = flat & 7, lid = flat >> 3;
    flat = (xcd < r ? xcd * (q + 1) : r * (q + 1) + (xcd - r) * q) + lid;
  }
  const int mBase = (flat / gx) * 64;
  const int nBase = (flat % gx) * 128;

  floatx4 acc[NW][4][2];
#pragma unroll
  for (int w = 0; w < NW; ++w)
#pragma unroll
    for (int mt = 0; mt < 4; ++mt)
#pragma unroll
      for (int nt = 0; nt < 2; ++nt)
#pragma unroll
        for (int r = 0; r < 4; ++r) acc[w][mt][nt][r] = 0.f;

  // A staging: 64 rows x 32 cols bf16 = 4KB = 256 lanes x 16B (one issue)
  int am = mBase + (tid >> 2);
  if (am > M - 1) am = M - 1;            // tail clamp (dup rows; stores guarded)
  const short* aSrc = A + (size_t)am * lda + (tid & 3) * 8;

  // B staging: NW * 128 rows x 32 cols = NW*2 issues
  const short* bSrc[NW * 2];
#pragma unroll
  for (int i = 0; i < NW * 2; ++i) {
    int t2 = tid + i * 256;
    int w  = t2 >> 9;
    int r  = (t2 >> 2) & 127;
    int c8 = (t2 & 3) * 8;
    bSrc[i] = Bt + (size_t)w * wstride + (size_t)(nBase + r) * ldb + c8;
  }

  auto stage = [&](int buf, int kk) {
    async_ld16(aSrc + kk, &lA[buf][tid * 8]);
#pragma unroll
    for (int i = 0; i < NW * 2; ++i)
      async_ld16(bSrc[i] + kk, &lB[buf][(tid + i * 256) * 8]);
  };

  const int nk = K >> 5;                 // K / 32 tiles
  const int kLast = (nk - 1) << 5;

  // prologue: stage tiles 0 and 1 (clamped), no drain
  stage(0, 0);
  stage(1, nk > 1 ? 32 : 0);

  int cur = 0;
  for (int t = 0; t < nk; ++t) {
    // my NEWEST NL loads may be outstanding; everything older (incl. tile t)
    // must be retired. Then barrier -> all waves' tile-t loads done.
    asm volatile("s_waitcnt vmcnt(%0)" :: "n"(NL) : "memory");
    __builtin_amdgcn_s_barrier();

    // compute tile t from buf[cur]
    short8 af[4];
#pragma unroll
    for (int mt = 0; mt < 4; ++mt)
      af[mt] = *(const short8*)(&lA[cur][(mt * 16 + l16) * 32 + quad * 8]);
#pragma unroll
    for (int w = 0; w < NW; ++w)
#pragma unroll
      for (int nt = 0; nt < 2; ++nt) {
        short8 bf = *(const short8*)(&lB[cur][(w * 128 + wave * 32 + nt * 16 + l16) * 32 + quad * 8]);
#pragma unroll
        for (int mt = 0; mt < 4; ++mt)
          acc[w][mt][nt] = __builtin_amdgcn_mfma_f32_16x16x32_bf16(
              af[mt], bf, acc[w][mt][nt], 0, 0, 0);
      }

    // my LDS reads retired; barrier -> all waves done reading buf[cur]
    asm volatile("s_waitcnt lgkmcnt(0)" ::: "memory");
    __builtin_amdgcn_s_barrier();

    // refill buf[cur] with tile t+2 (dummy re-stage of last tile past end:
    // keeps the outstanding count uniform so vmcnt(NL) stays correct)
    int nx = t + 2;
    stage(cur, nx < nk ? nx << 5 : kLast);
    cur ^= 1;
  }

  // ---- epilogue: C/D layout col=lane&15, row=quad*4+reg [m89/m91] ----
  const int colW = nBase + wave * 32;

  // hoisted per-lane biases (depend only on nt)
  float bb0[2], bb1[2], bb2[2];
  if (EPI == 1 || EPI == 2 || EPI == 3) {
#pragma unroll
    for (int nt = 0; nt < 2; ++nt) {
      int n = colW + nt * 16 + l16;
      bb0[nt] = bias0[n];
      if (EPI == 2 || EPI == 3) bb1[nt] = bias1[n];
      if (EPI == 2) bb2[nt] = bias2[n];
    }
  }

#pragma unroll
  for (int mt = 0; mt < 4; ++mt) {
    int mQ = mBase + mt * 16 + quad * 4;
#pragma unroll
    for (int r = 0; r < 4; ++r) {
      int m = mQ + r;
      if (m >= M) continue;
      int d = 0;
      const uint8_t* Pd = nullptr;
      const uint8_t* Ps = nullptr;
      if (EPI == 2 || EPI == 3) {
        d = dst[m];
        int s = src[m];
        Pd = Pn + (size_t)d * pstride;
        Ps = Pn + (size_t)s * pstride;
      }
#pragma unroll
      for (int nt = 0; nt < 2; ++nt) {
        int n = colW + nt * 16 + l16;
        float v0 = acc[0][mt][nt][r];
        if (EPI == 0) {
          // pair-interleaved P store: q<4 -> {T,M}x{f,s} pairs, q>=4 -> e slots
          int q = n / 768, j = n - q * 768;
          size_t o;
          if (q < 4) o = (size_t)(((q & 1) ? 1536 : 0) + 2 * j + ((q >> 1) & 1));
          else       o = (size_t)((q == 4) ? (3072 + j) : (3840 + j));
          ((uint8_t*)outP)[(size_t)m * ldout + o] = ftof8(v0);
        } else if (EPI == 1) {
          ((short*)outP)[(size_t)m * ldout + n] = f2b(tanh_fast(v0 + bb0[nt]));
        } else {
          uint32_t pt = *(const unsigned short*)(Pd + 2 * n);          // {f_top,s_top}
          uint32_t pm = *(const unsigned short*)(Ps + 1536 + 2 * n);   // {f_mid,s_mid}
          floatx2 vt = f8pair(pt);
          floatx2 vm = f8pair(pm);
          float hf = v0 + vt.x + vm.x + bb0[nt];
          float hs = acc[1][mt][nt][r] + vt.y + vm.y + bb1[nt];
          atomicAdd(&agg[(size_t)d * FF + n], fmaxf(hs, 0.f) * sigm(hf));
          if (EPI == 2) {
            float he = acc[2][mt][nt][r] + f8one(Pd[3072 + n]) + f8one(Ps[3840 + n]) + bb2[nt];
            float ev = b2f(eIn[(size_t)m * FF + n]);
            e2Out[(size_t)m * FF + n] = ftof8(ev * (1.f + sigm(he)));
          }
        }
      }
    }
  }
}

// ---------------------------------------------------------------------------
__global__ void conv_f2b(const float* __restrict__ in, short* __restrict__ out, int n) {
  int i = blockIdx.x * 256 + threadIdx.x;
  if (i < n) out[i] = f2b(in[i]);
}

// fp8 -> bf16, 4 elements/thread
__global__ void f8_to_b16(const uint8_t* __restrict__ in, short* __restrict__ out, int n4) {
  int i = blockIdx.x * 256 + threadIdx.x;
  if (i < n4) {
    uint32_t u = ((const uint32_t*)in)[i];
    floatx2 a = f8pair(u);
    floatx2 b = f8pair_hi(u);
    short4v o;
    o.x = f2b(a.x); o.y = f2b(a.y); o.z = f2b(b.x); o.w = f2b(b.y);
    ((short4v*)out)[i] = o;
  }
}

// tiled transpose: in[R][C] fp32 -> out[C][R] bf16, coalesced both sides
__global__ void transpose_wt(const float* __restrict__ in, short* __restrict__ out,
                             int R, int C) {
  __shared__ float t[32][33];
  int c0 = blockIdx.x * 32, r0 = blockIdx.y * 32;
  int tx = threadIdx.x, ty = threadIdx.y;
#pragma unroll
  for (int i = ty; i < 32; i += 8)
    t[i][tx] = in[(size_t)(r0 + i) * C + (c0 + tx)];
  __syncthreads();
#pragma unroll
  for (int i = ty; i < 32; i += 8)
    out[(size_t)(c0 + i) * R + (r0 + tx)] = f2b(t[tx][i]);
}

// x1 = x + agg ; write bf16 x1B and fp32 back into agg (in place)
__global__ void make_x1(const float* __restrict__ x, float* __restrict__ agg,
                        short* __restrict__ x1b, int n) {
  int i = blockIdx.x * 256 + threadIdx.x;
  if (i < n) {
    float v = x[i] + agg[i];
    agg[i] = v;
    x1b[i] = f2b(v);
  }
}

// pooled = colsum(agg)   (agg holds x2)
__global__ void pool_k(const float* __restrict__ agg, float* __restrict__ pooled) {
  int t = threadIdx.x;
  int r0 = blockIdx.x * 64;
  float s0 = 0.f, s1 = 0.f, s2 = 0.f;
  for (int r = 0; r < 64; ++r) {
    int row = r0 + r;
    if (row >= NN) break;
    size_t base = (size_t)row * FF;
    s0 += agg[base + t];
    s1 += agg[base + t + 256];
    s2 += agg[base + t + 512];
  }
  atomicAdd(&pooled[t], s0);
  atomicAdd(&pooled[t + 256], s1);
  atomicAdd(&pooled[t + 512], s2);
}

__global__ void head_k(const float* __restrict__ pooled, const float* __restrict__ Wd,
                       const float* __restrict__ bd, float* __restrict__ out) {
  int l = threadIdx.x;
  int ll = l & 15;
  float a = 0.f;
  for (int j = 0; j < FF; ++j) a += pooled[j] * Wd[j * 16 + ll];
  a += bd[ll];
  float mx = a;
  for (int off = 8; off; off >>= 1) mx = fmaxf(mx, __shfl_xor(mx, off, 16));
  float ex = __expf(a - mx), sm = ex;
  for (int off = 8; off; off >>= 1) sm += __shfl_xor(sm, off, 16);
  if (l < 16) out[l] = ex / sm;
}

__global__ void sentinel_k(float* __restrict__ out, int n) {
  int i = blockIdx.x * 256 + threadIdx.x;
  if (i < n) out[i] = -1.0f;   // ws too small marker -> absmax ~2.0
}

// ---------------------------------------------------------------------------
extern "C" void kernel_launch(void* const* d_in, const int* in_sizes, int n_in,
                              void* d_out, int out_size, void* d_ws, size_t ws_size,
                              hipStream_t stream) {
  const float* x     = (const float*)d_in[0];
  const float* e_raw = (const float*)d_in[1];
  const int*   src   = (const int*)d_in[2];
  const int*   dst   = (const int*)d_in[3];
  const float* W_pre = (const float*)d_in[4];
  const float* b_pre = (const float*)d_in[5];
  const float* Wf1   = (const float*)d_in[6];
  const float* bf1   = (const float*)d_in[7];
  const float* Ws1   = (const float*)d_in[8];
  const float* bs1   = (const float*)d_in[9];
  const float* We1   = (const float*)d_in[10];
  const float* be1   = (const float*)d_in[11];
  const float* Wf2   = (const float*)d_in[12];
  const float* bf2   = (const float*)d_in[13];
  const float* Ws2   = (const float*)d_in[14];
  const float* bs2   = (const float*)d_in[15];
  const float* Wd    = (const float*)d_in[18];
  const float* bd    = (const float*)d_in[19];
  float* out = (float*)d_out;

  // ---- base workspace (ws ~256 MB measured) ----
  char* w = (char*)d_ws;
  size_t off = 0;
  auto take = [&](size_t b) -> void* {
    void* p = w + off;
    off += (b + 255) & ~(size_t)255;
    return p;
  };
  uint8_t* P   = (uint8_t*)take((size_t)NN * 4608);     // fp8 node projections (pair layout)
  float* agg   = (float*)take((size_t)NN * FF * 4);     // agg1 -> x1 -> x2
  short* xB    = (short*)take((size_t)NN * FF * 2);     // x bf16, later x1 bf16
  uint8_t* e2  = (uint8_t*)take((size_t)EN * FF);       // e2 fp8 (full, 92.2 MB)
  short* WpreT = (short*)take((size_t)FF * 64 * 2);
  short* Wn1T  = (short*)take((size_t)6 * FF * FF * 2); // [fT fM sT sM eT eM]
  short* Wb1T  = (short*)take((size_t)3 * FF * FF * 2); // [f s e] bottoms
  short* Wn2T  = (short*)take((size_t)4 * FF * FF * 2); // [f2T f2M s2T s2M]
  short* Wb2T  = (short*)take((size_t)2 * FF * FF * 2); // [f2 s2] bottoms
  float* pooled= (float*)take((size_t)FF * 4);
  const size_t base = off;

  // ---- adaptive edge chunk (multiple of 64; 1664 B/edge: erC 128 + eC 1536) ----
  long long avail = (long long)ws_size - (long long)base - 4096;
  long long ecl = avail / 1664;
  int Ec = (int)(ecl < 0 ? 0 : ecl);
  Ec &= ~63;
  if (Ec > EN) Ec = EN;
  if (Ec < 64 || n_in < 20) {
    sentinel_k<<<(out_size + 255) / 256, 256, 0, stream>>>(out, out_size);
    return;
  }
  short* erC = (short*)take((size_t)Ec * 64 * 2);
  short* eC  = (short*)take((size_t)Ec * FF * 2);

  hipMemsetAsync(agg, 0, (size_t)NN * FF * 4, stream);
  hipMemsetAsync(pooled, 0, (size_t)FF * 4, stream);

  // x -> bf16
  conv_f2b<<<(NN * FF + 255) / 256, 256, 0, stream>>>(x, xB, NN * FF);

  // weight transposes (W[K,N] -> Wt[N,K] bf16), tiled/coalesced
  dim3 tb(32, 8);
  transpose_wt<<<dim3(24, 2), tb, 0, stream>>>(W_pre, WpreT, 64, FF);
  const float* Wc1[3] = {Wf1, Ws1, We1};
  for (int q = 0; q < 3; ++q) {
    for (int h = 0; h < 2; ++h)
      transpose_wt<<<dim3(24, 24), tb, 0, stream>>>(Wc1[q] + (size_t)h * FF * FF,
                                                    Wn1T + (size_t)(q * 2 + h) * FF * FF, FF, FF);
    transpose_wt<<<dim3(24, 24), tb, 0, stream>>>(Wc1[q] + (size_t)2 * FF * FF,
                                                  Wb1T + (size_t)q * FF * FF, FF, FF);
  }
  const float* Wc2[2] = {Wf2, Ws2};
  for (int q = 0; q < 2; ++q) {
    for (int h = 0; h < 2; ++h)
      transpose_wt<<<dim3(24, 24), tb, 0, stream>>>(Wc2[q] + (size_t)h * FF * FF,
                                                    Wn2T + (size_t)(q * 2 + h) * FF * FF, FF, FF);
    transpose_wt<<<dim3(24, 24), tb, 0, stream>>>(Wc2[q] + (size_t)2 * FF * FF,
                                                  Wb2T + (size_t)q * FF * FF, FF, FF);
  }

  dim3 blk(256);
  const int gy_n = (NN + 63) / 64;

  // P1 = x @ [fT fM sT sM eT eM] -> P fp8 pair layout
  gemm_fused<1, 0><<<dim3(36, gy_n), blk, 0, stream>>>(
      xB, FF, Wn1T, FF, 0, NN, 4608, FF, P, 4608,
      nullptr, nullptr, nullptr, nullptr, nullptr, nullptr, 0, nullptr, nullptr, nullptr);

  // ---- loop 1: conv1 msg + gate (NW=3), write e2 fp8 ----
  for (int eo = 0; eo < EN; eo += Ec) {
    int ec = EN - eo < Ec ? EN - eo : Ec;
    conv_f2b<<<(ec * 64 + 255) / 256, 256, 0, stream>>>(e_raw + (size_t)eo * 64, erC, ec * 64);
    gemm_fused<1, 1><<<dim3(6, ec / 64), blk, 0, stream>>>(
        erC, 64, WpreT, 64, 0, ec, FF, 64, eC, FF,
        b_pre, nullptr, nullptr, nullptr, nullptr, nullptr, 0, nullptr, nullptr, nullptr);
    gemm_fused<3, 2><<<dim3(6, ec / 64), blk, 0, stream>>>(
        eC, FF, Wb1T, FF, FF * FF, ec, FF, FF, nullptr, 0,
        bf1, bs1, be1, dst + eo, src + eo, P, 4608,
        eC, e2 + (size_t)eo * FF, agg);
  }

  // x1 = x + agg (agg in place; x1 bf16 into xB)
  make_x1<<<(NN * FF + 255) / 256, 256, 0, stream>>>(x, agg, xB, NN * FF);

  // P2 = x1 @ [f2T f2M s2T s2M] -> P pair regions (e slots unused now)
  gemm_fused<1, 0><<<dim3(24, gy_n), blk, 0, stream>>>(
      xB, FF, Wn2T, FF, 0, NN, 3072, FF, P, 4608,
      nullptr, nullptr, nullptr, nullptr, nullptr, nullptr, 0, nullptr, nullptr, nullptr);

  // ---- loop 2: e2 fp8 -> bf16, conv2 msg (NW=2) ----
  for (int eo = 0; eo < EN; eo += Ec) {
    int ec = EN - eo < Ec ? EN - eo : Ec;
    f8_to_b16<<<(ec * 192 + 255) / 256, 256, 0, stream>>>(e2 + (size_t)eo * FF, eC, ec * 192);
    gemm_fused<2, 3><<<dim3(6, ec / 64), blk, 0, stream>>>(
        eC, FF, Wb2T, FF, FF * FF, ec, FF, FF, nullptr, 0,
        bf2, bs2, nullptr, dst + eo, src + eo, P, 4608,
        nullptr, nullptr, agg);
  }

  // pooled = colsum(x2)
  pool_k<<<(NN + 63) / 64, blk, 0, stream>>>(agg, pooled);

  // out = softmax(pooled @ Wd + bd)
  head_k<<<1, 64, 0, stream>>>(pooled, Wd, bd, out);

  (void)in_sizes; (void)ws_size;
}

// Round 3
// 2123.935 us; speedup vs baseline: 1.2462x; 1.2462x over previous
//
#include <hip/hip_runtime.h>
#include <stdint.h>

#define EN 120000
#define NN 12000
#define FF 768

typedef __attribute__((ext_vector_type(8))) short short8;
typedef __attribute__((ext_vector_type(4))) short short4v;
typedef __attribute__((ext_vector_type(4))) float floatx4;
typedef __attribute__((ext_vector_type(2))) float floatx2;

#ifdef __has_builtin
#if __has_builtin(__builtin_amdgcn_cvt_pk_f32_fp8) && __has_builtin(__builtin_amdgcn_cvt_f32_fp8)
#define HAS_HW_FP8 1
#endif
#endif
#ifndef HAS_HW_FP8
#define HAS_HW_FP8 0
#endif

__device__ __forceinline__ float b2f(short u) {
  union { uint32_t i; float f; } v; v.i = ((uint32_t)(uint16_t)u) << 16; return v.f;
}
__device__ __forceinline__ short f2b(float f) {
  union { float f; uint32_t i; } v; v.f = f;
  uint32_t r = (v.i + 0x7fffu + ((v.i >> 16) & 1u)) >> 16;
  return (short)(uint16_t)r;
}
// fp8 e4m3fn software codec (OCP; exact via f32 subnormal scaling; RNE)
__device__ __forceinline__ float f8tof(uint32_t b) {
  union { uint32_t i; float f; } u;
  u.i = (b & 0x7f) << 20;
  float v = u.f * 0x1p120f;
  return (b & 0x80) ? -v : v;
}
__device__ __forceinline__ uint8_t ftof8(float v) {
  union { float f; uint32_t i; } u;
  u.f = fabsf(v) * 0x1p-120f;
  uint32_t r = (u.i + 0x7ffffu + ((u.i >> 20) & 1u)) >> 20;
  if (r > 0x7eu) r = 0x7eu;                 // clamp to 448, no inf/nan
  return (uint8_t)(r | ((v < 0.f) ? 0x80u : 0u));
}
__device__ __forceinline__ floatx2 f8pair(uint32_t u) {
#if HAS_HW_FP8
  return __builtin_amdgcn_cvt_pk_f32_fp8(u, false);
#else
  floatx2 r; r.x = f8tof(u & 0xff); r.y = f8tof((u >> 8) & 0xff); return r;
#endif
}
__device__ __forceinline__ float f8one(uint32_t u) {   // byte 0
#if HAS_HW_FP8
  return __builtin_amdgcn_cvt_f32_fp8(u, 0);
#else
  return f8tof(u & 0xff);
#endif
}
__device__ __forceinline__ float sigm(float x) { return 1.f / (1.f + __expf(-x)); }
__device__ __forceinline__ float tanh_fast(float x) {
  float ax = fabsf(x);
  float t = __expf(-2.f * ax);
  float r = (1.f - t) / (1.f + t);
  return copysignf(r, x);
}
__device__ __forceinline__ void async_ld16(const void* g, void* l) {
  __builtin_amdgcn_global_load_lds(
      (const __attribute__((address_space(1))) void*)g,
      (__attribute__((address_space(3))) void*)l, 16, 0, 0);
}

// ---------------------------------------------------------------------------
// Fused multi-weight GEMM: C_w[M,N] = A[M,K] @ Bt_w[N,K]^T, dtype by F8AB:
//   F8AB=0: bf16 inputs, BK=32;  F8AB=1: fp8 e4m3 inputs, BK=64.
// Both cases stage 64-BYTE K-rows, so staging/LDS geometry is identical:
// block tile 64(M) x 128(N), LDS 28KB single-buffered, 4 waves.
// K-loop = round-0 verified structure (sync; stage; sync; frags+MFMA).
// Block swizzle: bijective XCD remap (r1: FETCH 252->182MB on conv1).
//
// P node-row layout (fp8, 4608 B): [fsT pairs 1536 | fsM pairs 1536 | eT 768 | eM 768]
// EPI 0: store fp8 into P with pair-interleaved mapping (node projections)
// EPI 1: tanh(v + bias0) -> fp8 (pre_edge -> eC, consumed as fp8 A + gate input)
// EPI 2: conv1 msg atomics + gate -> e2 fp8 (NW=3: f,s,e)
// EPI 3: conv2 msg atomics (NW=2: f,s)
// All A/B/out strides are in BYTES. K is in elements.
// ---------------------------------------------------------------------------
template <int NW, int EPI, int F8AB>
__global__ __launch_bounds__(256, 2) void gemm_fused(
    const char* __restrict__ A, int lda,
    const char* __restrict__ Bt, int ldb, int wstride,
    int M, int K,
    void* __restrict__ outP, int ldout,
    const float* __restrict__ bias0, const float* __restrict__ bias1,
    const float* __restrict__ bias2,
    const int* __restrict__ dst, const int* __restrict__ src,
    const uint8_t* __restrict__ Pn, int pstride,
    const uint8_t* __restrict__ eInF8, uint8_t* __restrict__ e2Out,
    float* __restrict__ agg)
{
  __shared__ alignas(16) char lA[64 * 64];
  __shared__ alignas(16) char lB[NW * 128 * 64];

  const int tid  = threadIdx.x;
  const int wave = tid >> 6;
  const int lane = tid & 63;
  const int quad = lane >> 4;
  const int l16  = lane & 15;

  // ---- bijective XCD swizzle (m204 formula) ----
  const int gx  = gridDim.x;
  const int nwg = gx * gridDim.y;
  int flat = blockIdx.y * gx + blockIdx.x;
  {
    const int q = nwg >> 3, r = nwg & 7;
    const int xcd = flat & 7, lid = flat >> 3;
    flat = (xcd < r ? xcd * (q + 1) : r * (q + 1) + (xcd - r) * q) + lid;
  }
  const int mBase = (flat / gx) * 64;
  const int nBase = (flat % gx) * 128;

  floatx4 acc[NW][4][2];
#pragma unroll
  for (int w = 0; w < NW; ++w)
#pragma unroll
    for (int mt = 0; mt < 4; ++mt)
#pragma unroll
      for (int nt = 0; nt < 2; ++nt)
#pragma unroll
        for (int r = 0; r < 4; ++r) acc[w][mt][nt][r] = 0.f;

  // A staging: 64 rows x 64 BYTES = 4KB = 256 lanes x 16B (one issue)
  int am = mBase + (tid >> 2);
  if (am > M - 1) am = M - 1;            // tail clamp (dup rows; stores guarded)
  const char* aSrc = A + (size_t)am * lda + (tid & 3) * 16;

  // B staging: NW * 128 rows x 64 BYTES = NW*2 issues
  const char* bSrc[NW * 2];
#pragma unroll
  for (int i = 0; i < NW * 2; ++i) {
    int t2 = tid + i * 256;
    int w  = t2 >> 9;
    int r  = (t2 >> 2) & 127;
    bSrc[i] = Bt + (size_t)w * wstride + (size_t)(nBase + r) * ldb + (t2 & 3) * 16;
  }

  const int Kb = K * (F8AB ? 1 : 2);     // K in bytes

  for (int k0 = 0; k0 < Kb; k0 += 64) {
    __syncthreads();                     // prev iter LDS reads done
    async_ld16(aSrc + k0, lA + tid * 16);
#pragma unroll
    for (int i = 0; i < NW * 2; ++i)
      async_ld16(bSrc[i] + k0, lB + (tid + i * 256) * 16);
    __syncthreads();                     // barrier drains vmcnt -> staging done

    if constexpr (F8AB) {
      // fp8: two K=32 halves per 64B row; frag = 8 bytes (long)
      long af[4][2];
#pragma unroll
      for (int mt = 0; mt < 4; ++mt) {
        const char* rp = lA + (mt * 16 + l16) * 64 + quad * 8;
        af[mt][0] = *(const long*)rp;
        af[mt][1] = *(const long*)(rp + 32);
      }
#pragma unroll
      for (int w = 0; w < NW; ++w)
#pragma unroll
        for (int nt = 0; nt < 2; ++nt) {
          const char* rp = lB + (w * 128 + wave * 32 + nt * 16 + l16) * 64 + quad * 8;
          long bf0 = *(const long*)rp;
          long bf1 = *(const long*)(rp + 32);
#pragma unroll
          for (int mt = 0; mt < 4; ++mt) {
            acc[w][mt][nt] = __builtin_amdgcn_mfma_f32_16x16x32_fp8_fp8(
                af[mt][0], bf0, acc[w][mt][nt], 0, 0, 0);
            acc[w][mt][nt] = __builtin_amdgcn_mfma_f32_16x16x32_fp8_fp8(
                af[mt][1], bf1, acc[w][mt][nt], 0, 0, 0);
          }
        }
    } else {
      // bf16: one K=32 step per 64B row; frag = 16 bytes (short8)
      short8 af[4];
#pragma unroll
      for (int mt = 0; mt < 4; ++mt)
        af[mt] = *(const short8*)(lA + (mt * 16 + l16) * 64 + quad * 16);
#pragma unroll
      for (int w = 0; w < NW; ++w)
#pragma unroll
        for (int nt = 0; nt < 2; ++nt) {
          short8 bf = *(const short8*)(lB + (w * 128 + wave * 32 + nt * 16 + l16) * 64 + quad * 16);
#pragma unroll
          for (int mt = 0; mt < 4; ++mt)
            acc[w][mt][nt] = __builtin_amdgcn_mfma_f32_16x16x32_bf16(
                af[mt], bf, acc[w][mt][nt], 0, 0, 0);
        }
    }
  }

  // ---- epilogue: C/D layout col=lane&15, row=quad*4+reg [m89/m91] ----
  const int colW = nBase + wave * 32;

  float bb0[2], bb1[2], bb2[2];
  if (EPI == 1 || EPI == 2 || EPI == 3) {
#pragma unroll
    for (int nt = 0; nt < 2; ++nt) {
      int n = colW + nt * 16 + l16;
      bb0[nt] = bias0[n];
      if (EPI == 2 || EPI == 3) bb1[nt] = bias1[n];
      if (EPI == 2) bb2[nt] = bias2[n];
    }
  }

#pragma unroll
  for (int mt = 0; mt < 4; ++mt) {
    int mQ = mBase + mt * 16 + quad * 4;
#pragma unroll
    for (int r = 0; r < 4; ++r) {
      int m = mQ + r;
      if (m >= M) continue;
      int d = 0;
      const uint8_t* Pd = nullptr;
      const uint8_t* Ps = nullptr;
      if (EPI == 2 || EPI == 3) {
        d = dst[m];
        int s = src[m];
        Pd = Pn + (size_t)d * pstride;
        Ps = Pn + (size_t)s * pstride;
      }
#pragma unroll
      for (int nt = 0; nt < 2; ++nt) {
        int n = colW + nt * 16 + l16;
        float v0 = acc[0][mt][nt][r];
        if (EPI == 0) {
          // pair-interleaved P store: q<4 -> {T,M}x{f,s} pairs, q>=4 -> e slots
          int q = n / 768, j = n - q * 768;
          size_t o;
          if (q < 4) o = (size_t)(((q & 1) ? 1536 : 0) + 2 * j + ((q >> 1) & 1));
          else       o = (size_t)((q == 4) ? (3072 + j) : (3840 + j));
          ((uint8_t*)outP)[(size_t)m * ldout + o] = ftof8(v0);
        } else if (EPI == 1) {
          ((uint8_t*)outP)[(size_t)m * ldout + n] = ftof8(tanh_fast(v0 + bb0[nt]));
        } else {
          uint32_t pt = *(const unsigned short*)(Pd + 2 * n);          // {f_top,s_top}
          uint32_t pm = *(const unsigned short*)(Ps + 1536 + 2 * n);   // {f_mid,s_mid}
          floatx2 vt = f8pair(pt);
          floatx2 vm = f8pair(pm);
          float hf = v0 + vt.x + vm.x + bb0[nt];
          float hs = acc[1][mt][nt][r] + vt.y + vm.y + bb1[nt];
          atomicAdd(&agg[(size_t)d * FF + n], fmaxf(hs, 0.f) * sigm(hf));
          if (EPI == 2) {
            float he = acc[2][mt][nt][r] + f8one(Pd[3072 + n]) + f8one(Ps[3840 + n]) + bb2[nt];
            float ev = f8one(eInF8[(size_t)m * FF + n]);
            e2Out[(size_t)m * FF + n] = ftof8(ev * (1.f + sigm(he)));
          }
        }
      }
    }
  }
}

// ---------------------------------------------------------------------------
__global__ void conv_f2b(const float* __restrict__ in, short* __restrict__ out, int n) {
  int i = blockIdx.x * 256 + threadIdx.x;
  if (i < n) out[i] = f2b(in[i]);
}

// tiled transpose: in[R][C] fp32 -> out[C][R] bf16, coalesced both sides
__global__ void transpose_wt(const float* __restrict__ in, short* __restrict__ out,
                             int R, int C) {
  __shared__ float t[32][33];
  int c0 = blockIdx.x * 32, r0 = blockIdx.y * 32;
  int tx = threadIdx.x, ty = threadIdx.y;
#pragma unroll
  for (int i = ty; i < 32; i += 8)
    t[i][tx] = in[(size_t)(r0 + i) * C + (c0 + tx)];
  __syncthreads();
#pragma unroll
  for (int i = ty; i < 32; i += 8)
    out[(size_t)(c0 + i) * R + (r0 + tx)] = f2b(t[tx][i]);
}

// tiled transpose: in[R][C] fp32 -> out[C][R] fp8 e4m3
__global__ void transpose_wt8(const float* __restrict__ in, uint8_t* __restrict__ out,
                              int R, int C) {
  __shared__ float t[32][33];
  int c0 = blockIdx.x * 32, r0 = blockIdx.y * 32;
  int tx = threadIdx.x, ty = threadIdx.y;
#pragma unroll
  for (int i = ty; i < 32; i += 8)
    t[i][tx] = in[(size_t)(r0 + i) * C + (c0 + tx)];
  __syncthreads();
#pragma unroll
  for (int i = ty; i < 32; i += 8)
    out[(size_t)(c0 + i) * R + (r0 + tx)] = ftof8(t[tx][i]);
}

// x1 = x + agg ; write bf16 x1B and fp32 back into agg (in place)
__global__ void make_x1(const float* __restrict__ x, float* __restrict__ agg,
                        short* __restrict__ x1b, int n) {
  int i = blockIdx.x * 256 + threadIdx.x;
  if (i < n) {
    float v = x[i] + agg[i];
    agg[i] = v;
    x1b[i] = f2b(v);
  }
}

// pooled = colsum(agg)   (agg holds x2)
__global__ void pool_k(const float* __restrict__ agg, float* __restrict__ pooled) {
  int t = threadIdx.x;
  int r0 = blockIdx.x * 64;
  float s0 = 0.f, s1 = 0.f, s2 = 0.f;
  for (int r = 0; r < 64; ++r) {
    int row = r0 + r;
    if (row >= NN) break;
    size_t base = (size_t)row * FF;
    s0 += agg[base + t];
    s1 += agg[base + t + 256];
    s2 += agg[base + t + 512];
  }
  atomicAdd(&pooled[t], s0);
  atomicAdd(&pooled[t + 256], s1);
  atomicAdd(&pooled[t + 512], s2);
}

__global__ void head_k(const float* __restrict__ pooled, const float* __restrict__ Wd,
                       const float* __restrict__ bd, float* __restrict__ out) {
  int l = threadIdx.x;
  int ll = l & 15;
  float a = 0.f;
  for (int j = 0; j < FF; ++j) a += pooled[j] * Wd[j * 16 + ll];
  a += bd[ll];
  float mx = a;
  for (int off = 8; off; off >>= 1) mx = fmaxf(mx, __shfl_xor(mx, off, 16));
  float ex = __expf(a - mx), sm = ex;
  for (int off = 8; off; off >>= 1) sm += __shfl_xor(sm, off, 16);
  if (l < 16) out[l] = ex / sm;
}

__global__ void sentinel_k(float* __restrict__ out, int n) {
  int i = blockIdx.x * 256 + threadIdx.x;
  if (i < n) out[i] = -1.0f;   // ws too small marker -> absmax ~2.0
}

// ---------------------------------------------------------------------------
extern "C" void kernel_launch(void* const* d_in, const int* in_sizes, int n_in,
                              void* d_out, int out_size, void* d_ws, size_t ws_size,
                              hipStream_t stream) {
  const float* x     = (const float*)d_in[0];
  const float* e_raw = (const float*)d_in[1];
  const int*   src   = (const int*)d_in[2];
  const int*   dst   = (const int*)d_in[3];
  const float* W_pre = (const float*)d_in[4];
  const float* b_pre = (const float*)d_in[5];
  const float* Wf1   = (const float*)d_in[6];
  const float* bf1   = (const float*)d_in[7];
  const float* Ws1   = (const float*)d_in[8];
  const float* bs1   = (const float*)d_in[9];
  const float* We1   = (const float*)d_in[10];
  const float* be1   = (const float*)d_in[11];
  const float* Wf2   = (const float*)d_in[12];
  const float* bf2   = (const float*)d_in[13];
  const float* Ws2   = (const float*)d_in[14];
  const float* bs2   = (const float*)d_in[15];
  const float* Wd    = (const float*)d_in[18];
  const float* bd    = (const float*)d_in[19];
  float* out = (float*)d_out;

  // ---- base workspace (ws ~256 MB measured) ----
  char* w = (char*)d_ws;
  size_t off = 0;
  auto take = [&](size_t b) -> void* {
    void* p = w + off;
    off += (b + 255) & ~(size_t)255;
    return p;
  };
  uint8_t* P    = (uint8_t*)take((size_t)NN * 4608);     // fp8 node projections (pair layout)
  float* agg    = (float*)take((size_t)NN * FF * 4);     // agg1 -> x1 -> x2
  short* xB     = (short*)take((size_t)NN * FF * 2);     // x bf16, later x1 bf16
  uint8_t* e2   = (uint8_t*)take((size_t)EN * FF);       // e2 fp8 (full, 92.2 MB)
  short* WpreT  = (short*)take((size_t)FF * 64 * 2);
  short* Wn1T   = (short*)take((size_t)6 * FF * FF * 2); // [fT fM sT sM eT eM] bf16
  uint8_t* Wb1T = (uint8_t*)take((size_t)3 * FF * FF);   // [f s e] bottoms fp8
  short* Wn2T   = (short*)take((size_t)4 * FF * FF * 2); // [f2T f2M s2T s2M] bf16
  uint8_t* Wb2T = (uint8_t*)take((size_t)2 * FF * FF);   // [f2 s2] bottoms fp8
  float* pooled = (float*)take((size_t)FF * 4);
  const size_t base = off;

  // ---- adaptive edge chunk (multiple of 64; 896 B/edge: erC 128 + eC 768) ----
  long long avail = (long long)ws_size - (long long)base - 4096;
  long long ecl = avail / 896;
  int Ec = (int)(ecl < 0 ? 0 : ecl);
  Ec &= ~63;
  if (Ec > EN) Ec = EN;
  if (Ec < 64 || n_in < 20) {
    sentinel_k<<<(out_size + 255) / 256, 256, 0, stream>>>(out, out_size);
    return;
  }
  short* erC   = (short*)take((size_t)Ec * 64 * 2);
  uint8_t* eC  = (uint8_t*)take((size_t)Ec * FF);        // pre_edge out, fp8

  hipMemsetAsync(agg, 0, (size_t)NN * FF * 4, stream);
  hipMemsetAsync(pooled, 0, (size_t)FF * 4, stream);

  // x -> bf16
  conv_f2b<<<(NN * FF + 255) / 256, 256, 0, stream>>>(x, xB, NN * FF);

  // weight transposes (W[K,N] -> Wt[N,K]), tiled/coalesced
  dim3 tb(32, 8);
  transpose_wt<<<dim3(24, 2), tb, 0, stream>>>(W_pre, WpreT, 64, FF);
  const float* Wc1[3] = {Wf1, Ws1, We1};
  for (int q = 0; q < 3; ++q) {
    for (int h = 0; h < 2; ++h)
      transpose_wt<<<dim3(24, 24), tb, 0, stream>>>(Wc1[q] + (size_t)h * FF * FF,
                                                    Wn1T + (size_t)(q * 2 + h) * FF * FF, FF, FF);
    transpose_wt8<<<dim3(24, 24), tb, 0, stream>>>(Wc1[q] + (size_t)2 * FF * FF,
                                                   Wb1T + (size_t)q * FF * FF, FF, FF);
  }
  const float* Wc2[2] = {Wf2, Ws2};
  for (int q = 0; q < 2; ++q) {
    for (int h = 0; h < 2; ++h)
      transpose_wt<<<dim3(24, 24), tb, 0, stream>>>(Wc2[q] + (size_t)h * FF * FF,
                                                    Wn2T + (size_t)(q * 2 + h) * FF * FF, FF, FF);
    transpose_wt8<<<dim3(24, 24), tb, 0, stream>>>(Wc2[q] + (size_t)2 * FF * FF,
                                                   Wb2T + (size_t)q * FF * FF, FF, FF);
  }

  dim3 blk(256);
  const int gy_n = (NN + 63) / 64;

  // P1 = x @ [fT fM sT sM eT eM] -> P fp8 pair layout (bf16 GEMM)
  gemm_fused<1, 0, 0><<<dim3(36, gy_n), blk, 0, stream>>>(
      (const char*)xB, FF * 2, (const char*)Wn1T, FF * 2, 0, NN, FF, P, 4608,
      nullptr, nullptr, nullptr, nullptr, nullptr, nullptr, 0, nullptr, nullptr, nullptr);

  // ---- loop 1: pre_edge (bf16 -> fp8 eC), conv1 msg+gate (fp8, NW=3) ----
  for (int eo = 0; eo < EN; eo += Ec) {
    int ec = EN - eo < Ec ? EN - eo : Ec;
    conv_f2b<<<(ec * 64 + 255) / 256, 256, 0, stream>>>(e_raw + (size_t)eo * 64, erC, ec * 64);
    gemm_fused<1, 1, 0><<<dim3(6, ec / 64), blk, 0, stream>>>(
        (const char*)erC, 64 * 2, (const char*)WpreT, 64 * 2, 0, ec, 64, eC, FF,
        b_pre, nullptr, nullptr, nullptr, nullptr, nullptr, 0, nullptr, nullptr, nullptr);
    gemm_fused<3, 2, 1><<<dim3(6, ec / 64), blk, 0, stream>>>(
        (const char*)eC, FF, (const char*)Wb1T, FF, FF * FF, ec, FF, nullptr, 0,
        bf1, bs1, be1, dst + eo, src + eo, P, 4608,
        eC, e2 + (size_t)eo * FF, agg);
  }

  // x1 = x + agg (agg in place; x1 bf16 into xB)
  make_x1<<<(NN * FF + 255) / 256, 256, 0, stream>>>(x, agg, xB, NN * FF);

  // P2 = x1 @ [f2T f2M s2T s2M] -> P pair regions (bf16 GEMM)
  gemm_fused<1, 0, 0><<<dim3(24, gy_n), blk, 0, stream>>>(
      (const char*)xB, FF * 2, (const char*)Wn2T, FF * 2, 0, NN, FF, P, 4608,
      nullptr, nullptr, nullptr, nullptr, nullptr, nullptr, 0, nullptr, nullptr, nullptr);

  // ---- conv2: single dispatch, A = e2 fp8 in place (NW=2) ----
  gemm_fused<2, 3, 1><<<dim3(6, EN / 64), blk, 0, stream>>>(
      (const char*)e2, FF, (const char*)Wb2T, FF, FF * FF, EN, FF, nullptr, 0,
      bf2, bs2, nullptr, dst, src, P, 4608,
      nullptr, nullptr, agg);

  // pooled = colsum(x2)
  pool_k<<<(NN + 63) / 64, blk, 0, stream>>>(agg, pooled);

  // out = softmax(pooled @ Wd + bd)
  head_k<<<1, 64, 0, stream>>>(pooled, Wd, bd, out);

  (void)in_sizes; (void)ws_size;
}

// Round 4
// 1839.188 us; speedup vs baseline: 1.4392x; 1.1548x over previous
//
#include <hip/hip_runtime.h>
#include <stdint.h>

#define EN 120000
#define NN 12000
#define FF 768

typedef __attribute__((ext_vector_type(8))) short short8;
typedef __attribute__((ext_vector_type(4))) short short4v;
typedef __attribute__((ext_vector_type(4))) float floatx4;
typedef __attribute__((ext_vector_type(2))) float floatx2;
typedef __attribute__((ext_vector_type(2))) long long2v;

#ifdef __has_builtin
#if __has_builtin(__builtin_amdgcn_cvt_pk_f32_fp8) && __has_builtin(__builtin_amdgcn_cvt_f32_fp8)
#define HAS_HW_FP8 1
#endif
#endif
#ifndef HAS_HW_FP8
#define HAS_HW_FP8 0
#endif

__device__ __forceinline__ float b2f(short u) {
  union { uint32_t i; float f; } v; v.i = ((uint32_t)(uint16_t)u) << 16; return v.f;
}
__device__ __forceinline__ short f2b(float f) {
  union { float f; uint32_t i; } v; v.f = f;
  uint32_t r = (v.i + 0x7fffu + ((v.i >> 16) & 1u)) >> 16;
  return (short)(uint16_t)r;
}
// fp8 e4m3fn software codec (OCP; exact via f32 subnormal scaling; RNE)
__device__ __forceinline__ float f8tof(uint32_t b) {
  union { uint32_t i; float f; } u;
  u.i = (b & 0x7f) << 20;
  float v = u.f * 0x1p120f;
  return (b & 0x80) ? -v : v;
}
__device__ __forceinline__ uint8_t ftof8(float v) {
  union { float f; uint32_t i; } u;
  u.f = fabsf(v) * 0x1p-120f;
  uint32_t r = (u.i + 0x7ffffu + ((u.i >> 20) & 1u)) >> 20;
  if (r > 0x7eu) r = 0x7eu;                 // clamp to 448, no inf/nan
  return (uint8_t)(r | ((v < 0.f) ? 0x80u : 0u));
}
__device__ __forceinline__ floatx2 f8pair(uint32_t u) {
#if HAS_HW_FP8
  return __builtin_amdgcn_cvt_pk_f32_fp8(u, false);
#else
  floatx2 r; r.x = f8tof(u & 0xff); r.y = f8tof((u >> 8) & 0xff); return r;
#endif
}
__device__ __forceinline__ float f8one(uint32_t u) {   // byte 0
#if HAS_HW_FP8
  return __builtin_amdgcn_cvt_f32_fp8(u, 0);
#else
  return f8tof(u & 0xff);
#endif
}
__device__ __forceinline__ float sigm(float x) { return 1.f / (1.f + __expf(-x)); }
__device__ __forceinline__ float tanh_fast(float x) {
  float ax = fabsf(x);
  float t = __expf(-2.f * ax);
  float r = (1.f - t) / (1.f + t);
  return copysignf(r, x);
}
__device__ __forceinline__ void async_ld16(const void* g, void* l) {
  __builtin_amdgcn_global_load_lds(
      (const __attribute__((address_space(1))) void*)g,
      (__attribute__((address_space(3))) void*)l, 16, 0, 0);
}
// fp8 K-interleave: within each 64-byte K-group, logical 8B-slot s
// (s = (k>>3)&7) is stored at byte (s&3)*16 + (s>>2)*8. One ds_read_b128 at
// quad*16 then yields lane quad's operands for BOTH K=32 MFMA halves ->
// b128 reads at the bank floor (fixes r3's 2.4e8 b64 conflicts).
__device__ __forceinline__ int permk(int n) {
  return (n & ~63) | (((n >> 3) & 3) << 4) | (((n >> 5) & 1) << 3) | (n & 7);
}

// ---------------------------------------------------------------------------
// Fused multi-weight GEMM: C_w[M,N] = A[M,K] @ Bt_w[N,K]^T, dtype by F8AB:
//   F8AB=0: bf16 inputs, BK=32;  F8AB=1: fp8 e4m3 inputs (K-interleaved), BK=64.
// Both cases stage 64-BYTE K-rows: block tile 64(M) x 128(N), LDS single-buf,
// 4 waves. K-loop = round-0 verified structure. Bijective XCD block swizzle.
//
// P node-row layout (fp8, 4608 B): [fsT pairs 1536 | fsM pairs 1536 | eT 768 | eM 768]
// EPI 0: store fp8 into P with pair-interleaved mapping (node projections)
// EPI 1: tanh(v + bias0) -> fp8 (pre_edge -> eC, K-interleaved store)
// EPI 2: conv1 msg atomics + gate -> e2 fp8 (NW=3: f,s,e); e2 K-interleaved
// EPI 3: conv2 msg atomics (NW=2: f,s)
// All A/B/out strides are in BYTES. K is in elements.
// ---------------------------------------------------------------------------
template <int NW, int EPI, int F8AB>
__global__ __launch_bounds__(256, 2) void gemm_fused(
    const char* __restrict__ A, int lda,
    const char* __restrict__ Bt, int ldb, int wstride,
    int M, int K,
    void* __restrict__ outP, int ldout,
    const float* __restrict__ bias0, const float* __restrict__ bias1,
    const float* __restrict__ bias2,
    const int* __restrict__ dst, const int* __restrict__ src,
    const uint8_t* __restrict__ Pn, int pstride,
    const uint8_t* __restrict__ eInF8, uint8_t* __restrict__ e2Out,
    float* __restrict__ agg)
{
  __shared__ alignas(16) char lA[64 * 64];
  __shared__ alignas(16) char lB[NW * 128 * 64];

  const int tid  = threadIdx.x;
  const int wave = tid >> 6;
  const int lane = tid & 63;
  const int quad = lane >> 4;
  const int l16  = lane & 15;

  // ---- bijective XCD swizzle (m204 formula) ----
  const int gx  = gridDim.x;
  const int nwg = gx * gridDim.y;
  int flat = blockIdx.y * gx + blockIdx.x;
  {
    const int q = nwg >> 3, r = nwg & 7;
    const int xcd = flat & 7, lid = flat >> 3;
    flat = (xcd < r ? xcd * (q + 1) : r * (q + 1) + (xcd - r) * q) + lid;
  }
  const int mBase = (flat / gx) * 64;
  const int nBase = (flat % gx) * 128;

  floatx4 acc[NW][4][2];
#pragma unroll
  for (int w = 0; w < NW; ++w)
#pragma unroll
    for (int mt = 0; mt < 4; ++mt)
#pragma unroll
      for (int nt = 0; nt < 2; ++nt)
#pragma unroll
        for (int r = 0; r < 4; ++r) acc[w][mt][nt][r] = 0.f;

  // A staging: 64 rows x 64 BYTES = 4KB = 256 lanes x 16B (one issue)
  int am = mBase + (tid >> 2);
  if (am > M - 1) am = M - 1;            // tail clamp (dup rows; stores guarded)
  const char* aSrc = A + (size_t)am * lda + (tid & 3) * 16;

  // B staging: NW * 128 rows x 64 BYTES = NW*2 issues
  const char* bSrc[NW * 2];
#pragma unroll
  for (int i = 0; i < NW * 2; ++i) {
    int t2 = tid + i * 256;
    int w  = t2 >> 9;
    int r  = (t2 >> 2) & 127;
    bSrc[i] = Bt + (size_t)w * wstride + (size_t)(nBase + r) * ldb + (t2 & 3) * 16;
  }

  const int Kb = K * (F8AB ? 1 : 2);     // K in bytes

  for (int k0 = 0; k0 < Kb; k0 += 64) {
    __syncthreads();                     // prev iter LDS reads done
    async_ld16(aSrc + k0, lA + tid * 16);
#pragma unroll
    for (int i = 0; i < NW * 2; ++i)
      async_ld16(bSrc[i] + k0, lB + (tid + i * 256) * 16);
    __syncthreads();                     // barrier drains vmcnt -> staging done

    if constexpr (F8AB) {
      // fp8 K-interleaved: ONE b128 per fragment = {k-half0, k-half1} operands
      long2v av[4];
#pragma unroll
      for (int mt = 0; mt < 4; ++mt)
        av[mt] = *(const long2v*)(lA + (mt * 16 + l16) * 64 + quad * 16);
#pragma unroll
      for (int w = 0; w < NW; ++w)
#pragma unroll
        for (int nt = 0; nt < 2; ++nt) {
          long2v bv = *(const long2v*)(lB + (w * 128 + wave * 32 + nt * 16 + l16) * 64 + quad * 16);
#pragma unroll
          for (int mt = 0; mt < 4; ++mt) {
            acc[w][mt][nt] = __builtin_amdgcn_mfma_f32_16x16x32_fp8_fp8(
                av[mt].x, bv.x, acc[w][mt][nt], 0, 0, 0);
            acc[w][mt][nt] = __builtin_amdgcn_mfma_f32_16x16x32_fp8_fp8(
                av[mt].y, bv.y, acc[w][mt][nt], 0, 0, 0);
          }
        }
    } else {
      // bf16: one K=32 step per 64B row; frag = 16 bytes (short8)
      short8 af[4];
#pragma unroll
      for (int mt = 0; mt < 4; ++mt)
        af[mt] = *(const short8*)(lA + (mt * 16 + l16) * 64 + quad * 16);
#pragma unroll
      for (int w = 0; w < NW; ++w)
#pragma unroll
        for (int nt = 0; nt < 2; ++nt) {
          short8 bf = *(const short8*)(lB + (w * 128 + wave * 32 + nt * 16 + l16) * 64 + quad * 16);
#pragma unroll
          for (int mt = 0; mt < 4; ++mt)
            acc[w][mt][nt] = __builtin_amdgcn_mfma_f32_16x16x32_bf16(
                af[mt], bf, acc[w][mt][nt], 0, 0, 0);
        }
    }
  }

  // ---- epilogue: C/D layout col=lane&15, row=quad*4+reg [m89/m91] ----
  const int colW = nBase + wave * 32;

  float bb0[2], bb1[2], bb2[2];
  if (EPI == 1 || EPI == 2 || EPI == 3) {
#pragma unroll
    for (int nt = 0; nt < 2; ++nt) {
      int n = colW + nt * 16 + l16;
      bb0[nt] = bias0[n];
      if (EPI == 2 || EPI == 3) bb1[nt] = bias1[n];
      if (EPI == 2) bb2[nt] = bias2[n];
    }
  }

#pragma unroll
  for (int mt = 0; mt < 4; ++mt) {
    int mQ = mBase + mt * 16 + quad * 4;
#pragma unroll
    for (int r = 0; r < 4; ++r) {
      int m = mQ + r;
      if (m >= M) continue;
      int d = 0;
      const uint8_t* Pd = nullptr;
      const uint8_t* Ps = nullptr;
      if (EPI == 2 || EPI == 3) {
        d = dst[m];
        int s = src[m];
        Pd = Pn + (size_t)d * pstride;
        Ps = Pn + (size_t)s * pstride;
      }
#pragma unroll
      for (int nt = 0; nt < 2; ++nt) {
        int n = colW + nt * 16 + l16;
        float v0 = acc[0][mt][nt][r];
        if (EPI == 0) {
          // pair-interleaved P store: q<4 -> {T,M}x{f,s} pairs, q>=4 -> e slots
          int q = n / 768, j = n - q * 768;
          size_t o;
          if (q < 4) o = (size_t)(((q & 1) ? 1536 : 0) + 2 * j + ((q >> 1) & 1));
          else       o = (size_t)((q == 4) ? (3072 + j) : (3840 + j));
          ((uint8_t*)outP)[(size_t)m * ldout + o] = ftof8(v0);
        } else if (EPI == 1) {
          ((uint8_t*)outP)[(size_t)m * ldout + permk(n)] = ftof8(tanh_fast(v0 + bb0[nt]));
        } else {
          uint32_t pt = *(const unsigned short*)(Pd + 2 * n);          // {f_top,s_top}
          uint32_t pm = *(const unsigned short*)(Ps + 1536 + 2 * n);   // {f_mid,s_mid}
          floatx2 vt = f8pair(pt);
          floatx2 vm = f8pair(pm);
          float hf = v0 + vt.x + vm.x + bb0[nt];
          float hs = acc[1][mt][nt][r] + vt.y + vm.y + bb1[nt];
          atomicAdd(&agg[(size_t)d * FF + n], fmaxf(hs, 0.f) * sigm(hf));
          if (EPI == 2) {
            float he = acc[2][mt][nt][r] + f8one(Pd[3072 + n]) + f8one(Ps[3840 + n]) + bb2[nt];
            float ev = f8one(eInF8[(size_t)m * FF + permk(n)]);
            e2Out[(size_t)m * FF + permk(n)] = ftof8(ev * (1.f + sigm(he)));
          }
        }
      }
    }
  }
}

// ---------------------------------------------------------------------------
__global__ void conv_f2b(const float* __restrict__ in, short* __restrict__ out, int n) {
  int i = blockIdx.x * 256 + threadIdx.x;
  if (i < n) out[i] = f2b(in[i]);
}

// tiled transpose: in[R][C] fp32 -> out[C][R] bf16, coalesced both sides
__global__ void transpose_wt(const float* __restrict__ in, short* __restrict__ out,
                             int R, int C) {
  __shared__ float t[32][33];
  int c0 = blockIdx.x * 32, r0 = blockIdx.y * 32;
  int tx = threadIdx.x, ty = threadIdx.y;
#pragma unroll
  for (int i = ty; i < 32; i += 8)
    t[i][tx] = in[(size_t)(r0 + i) * C + (c0 + tx)];
  __syncthreads();
#pragma unroll
  for (int i = ty; i < 32; i += 8)
    out[(size_t)(c0 + i) * R + (r0 + tx)] = f2b(t[tx][i]);
}

// tiled transpose: in[R][C] fp32 -> out[C][R] fp8 e4m3, K-interleaved columns
__global__ void transpose_wt8(const float* __restrict__ in, uint8_t* __restrict__ out,
                              int R, int C) {
  __shared__ float t[32][33];
  int c0 = blockIdx.x * 32, r0 = blockIdx.y * 32;
  int tx = threadIdx.x, ty = threadIdx.y;
#pragma unroll
  for (int i = ty; i < 32; i += 8)
    t[i][tx] = in[(size_t)(r0 + i) * C + (c0 + tx)];
  __syncthreads();
#pragma unroll
  for (int i = ty; i < 32; i += 8)
    out[(size_t)(c0 + i) * R + permk(r0 + tx)] = ftof8(t[tx][i]);
}

// x1 = x + agg ; write bf16 x1B and fp32 back into agg (in place)
__global__ void make_x1(const float* __restrict__ x, float* __restrict__ agg,
                        short* __restrict__ x1b, int n) {
  int i = blockIdx.x * 256 + threadIdx.x;
  if (i < n) {
    float v = x[i] + agg[i];
    agg[i] = v;
    x1b[i] = f2b(v);
  }
}

// pooled = colsum(agg)   (agg holds x2)
__global__ void pool_k(const float* __restrict__ agg, float* __restrict__ pooled) {
  int t = threadIdx.x;
  int r0 = blockIdx.x * 64;
  float s0 = 0.f, s1 = 0.f, s2 = 0.f;
  for (int r = 0; r < 64; ++r) {
    int row = r0 + r;
    if (row >= NN) break;
    size_t base = (size_t)row * FF;
    s0 += agg[base + t];
    s1 += agg[base + t + 256];
    s2 += agg[base + t + 512];
  }
  atomicAdd(&pooled[t], s0);
  atomicAdd(&pooled[t + 256], s1);
  atomicAdd(&pooled[t + 512], s2);
}

__global__ void head_k(const float* __restrict__ pooled, const float* __restrict__ Wd,
                       const float* __restrict__ bd, float* __restrict__ out) {
  int l = threadIdx.x;
  int ll = l & 15;
  float a = 0.f;
  for (int j = 0; j < FF; ++j) a += pooled[j] * Wd[j * 16 + ll];
  a += bd[ll];
  float mx = a;
  for (int off = 8; off; off >>= 1) mx = fmaxf(mx, __shfl_xor(mx, off, 16));
  float ex = __expf(a - mx), sm = ex;
  for (int off = 8; off; off >>= 1) sm += __shfl_xor(sm, off, 16);
  if (l < 16) out[l] = ex / sm;
}

__global__ void sentinel_k(float* __restrict__ out, int n) {
  int i = blockIdx.x * 256 + threadIdx.x;
  if (i < n) out[i] = -1.0f;   // ws too small marker -> absmax ~2.0
}

// ---------------------------------------------------------------------------
extern "C" void kernel_launch(void* const* d_in, const int* in_sizes, int n_in,
                              void* d_out, int out_size, void* d_ws, size_t ws_size,
                              hipStream_t stream) {
  const float* x     = (const float*)d_in[0];
  const float* e_raw = (const float*)d_in[1];
  const int*   src   = (const int*)d_in[2];
  const int*   dst   = (const int*)d_in[3];
  const float* W_pre = (const float*)d_in[4];
  const float* b_pre = (const float*)d_in[5];
  const float* Wf1   = (const float*)d_in[6];
  const float* bf1   = (const float*)d_in[7];
  const float* Ws1   = (const float*)d_in[8];
  const float* bs1   = (const float*)d_in[9];
  const float* We1   = (const float*)d_in[10];
  const float* be1   = (const float*)d_in[11];
  const float* Wf2   = (const float*)d_in[12];
  const float* bf2   = (const float*)d_in[13];
  const float* Ws2   = (const float*)d_in[14];
  const float* bs2   = (const float*)d_in[15];
  const float* Wd    = (const float*)d_in[18];
  const float* bd    = (const float*)d_in[19];
  float* out = (float*)d_out;

  // ---- base workspace (ws ~256 MB measured) ----
  char* w = (char*)d_ws;
  size_t off = 0;
  auto take = [&](size_t b) -> void* {
    void* p = w + off;
    off += (b + 255) & ~(size_t)255;
    return p;
  };
  uint8_t* P    = (uint8_t*)take((size_t)NN * 4608);     // fp8 node projections (pair layout)
  float* agg    = (float*)take((size_t)NN * FF * 4);     // agg1 -> x1 -> x2
  short* xB     = (short*)take((size_t)NN * FF * 2);     // x bf16, later x1 bf16
  uint8_t* e2   = (uint8_t*)take((size_t)EN * FF);       // e2 fp8 (full, K-interleaved)
  short* WpreT  = (short*)take((size_t)FF * 64 * 2);
  short* Wn1T   = (short*)take((size_t)6 * FF * FF * 2); // [fT fM sT sM eT eM] bf16
  uint8_t* Wb1T = (uint8_t*)take((size_t)3 * FF * FF);   // [f s e] bottoms fp8 (K-ilv)
  short* Wn2T   = (short*)take((size_t)4 * FF * FF * 2); // [f2T f2M s2T s2M] bf16
  uint8_t* Wb2T = (uint8_t*)take((size_t)2 * FF * FF);   // [f2 s2] bottoms fp8 (K-ilv)
  float* pooled = (float*)take((size_t)FF * 4);
  const size_t base = off;

  // ---- adaptive edge chunk (multiple of 64; 896 B/edge: erC 128 + eC 768) ----
  long long avail = (long long)ws_size - (long long)base - 4096;
  long long ecl = avail / 896;
  int Ec = (int)(ecl < 0 ? 0 : ecl);
  Ec &= ~63;
  if (Ec > EN) Ec = EN;
  if (Ec < 64 || n_in < 20) {
    sentinel_k<<<(out_size + 255) / 256, 256, 0, stream>>>(out, out_size);
    return;
  }
  short* erC   = (short*)take((size_t)Ec * 64 * 2);
  uint8_t* eC  = (uint8_t*)take((size_t)Ec * FF);        // pre_edge out, fp8 K-ilv

  hipMemsetAsync(agg, 0, (size_t)NN * FF * 4, stream);
  hipMemsetAsync(pooled, 0, (size_t)FF * 4, stream);

  // x -> bf16
  conv_f2b<<<(NN * FF + 255) / 256, 256, 0, stream>>>(x, xB, NN * FF);

  // weight transposes (W[K,N] -> Wt[N,K]), tiled/coalesced
  dim3 tb(32, 8);
  transpose_wt<<<dim3(24, 2), tb, 0, stream>>>(W_pre, WpreT, 64, FF);
  const float* Wc1[3] = {Wf1, Ws1, We1};
  for (int q = 0; q < 3; ++q) {
    for (int h = 0; h < 2; ++h)
      transpose_wt<<<dim3(24, 24), tb, 0, stream>>>(Wc1[q] + (size_t)h * FF * FF,
                                                    Wn1T + (size_t)(q * 2 + h) * FF * FF, FF, FF);
    transpose_wt8<<<dim3(24, 24), tb, 0, stream>>>(Wc1[q] + (size_t)2 * FF * FF,
                                                   Wb1T + (size_t)q * FF * FF, FF, FF);
  }
  const float* Wc2[2] = {Wf2, Ws2};
  for (int q = 0; q < 2; ++q) {
    for (int h = 0; h < 2; ++h)
      transpose_wt<<<dim3(24, 24), tb, 0, stream>>>(Wc2[q] + (size_t)h * FF * FF,
                                                    Wn2T + (size_t)(q * 2 + h) * FF * FF, FF, FF);
    transpose_wt8<<<dim3(24, 24), tb, 0, stream>>>(Wc2[q] + (size_t)2 * FF * FF,
                                                   Wb2T + (size_t)q * FF * FF, FF, FF);
  }

  dim3 blk(256);
  const int gy_n = (NN + 63) / 64;

  // P1 = x @ [fT fM sT sM eT eM] -> P fp8 pair layout (bf16 GEMM)
  gemm_fused<1, 0, 0><<<dim3(36, gy_n), blk, 0, stream>>>(
      (const char*)xB, FF * 2, (const char*)Wn1T, FF * 2, 0, NN, FF, P, 4608,
      nullptr, nullptr, nullptr, nullptr, nullptr, nullptr, 0, nullptr, nullptr, nullptr);

  // ---- loop 1: pre_edge (bf16 -> fp8 eC), conv1 msg+gate (fp8, NW=3) ----
  for (int eo = 0; eo < EN; eo += Ec) {
    int ec = EN - eo < Ec ? EN - eo : Ec;
    conv_f2b<<<(ec * 64 + 255) / 256, 256, 0, stream>>>(e_raw + (size_t)eo * 64, erC, ec * 64);
    gemm_fused<1, 1, 0><<<dim3(6, ec / 64), blk, 0, stream>>>(
        (const char*)erC, 64 * 2, (const char*)WpreT, 64 * 2, 0, ec, 64, eC, FF,
        b_pre, nullptr, nullptr, nullptr, nullptr, nullptr, 0, nullptr, nullptr, nullptr);
    gemm_fused<3, 2, 1><<<dim3(6, ec / 64), blk, 0, stream>>>(
        (const char*)eC, FF, (const char*)Wb1T, FF, FF * FF, ec, FF, nullptr, 0,
        bf1, bs1, be1, dst + eo, src + eo, P, 4608,
        eC, e2 + (size_t)eo * FF, agg);
  }

  // x1 = x + agg (agg in place; x1 bf16 into xB)
  make_x1<<<(NN * FF + 255) / 256, 256, 0, stream>>>(x, agg, xB, NN * FF);

  // P2 = x1 @ [f2T f2M s2T s2M] -> P pair regions (bf16 GEMM)
  gemm_fused<1, 0, 0><<<dim3(24, gy_n), blk, 0, stream>>>(
      (const char*)xB, FF * 2, (const char*)Wn2T, FF * 2, 0, NN, FF, P, 4608,
      nullptr, nullptr, nullptr, nullptr, nullptr, nullptr, 0, nullptr, nullptr, nullptr);

  // ---- conv2: single dispatch, A = e2 fp8 in place (NW=2) ----
  gemm_fused<2, 3, 1><<<dim3(6, EN / 64), blk, 0, stream>>>(
      (const char*)e2, FF, (const char*)Wb2T, FF, FF * FF, EN, FF, nullptr, 0,
      bf2, bs2, nullptr, dst, src, P, 4608,
      nullptr, nullptr, agg);

  // pooled = colsum(x2)
  pool_k<<<(NN + 63) / 64, blk, 0, stream>>>(agg, pooled);

  // out = softmax(pooled @ Wd + bd)
  head_k<<<1, 64, 0, stream>>>(pooled, Wd, bd, out);

  (void)in_sizes; (void)ws_size;
}